// Round 12
// baseline (1323.002 us; speedup 1.0000x reference)
//
#include <hip/hip_runtime.h>
#include <hip/hip_bf16.h>
#include <hip/hip_fp16.h>

#define Bn 256
#define Sn 1024
#define Hn 256
#define Vn 128
#define En 128

typedef _Float16 f16x8 __attribute__((ext_vector_type(8)));
typedef _Float16 f16x2 __attribute__((ext_vector_type(2)));
typedef float f32x4 __attribute__((ext_vector_type(4)));
typedef unsigned long long u64;
typedef unsigned int u32;

#define LOG2E2 2.885390081777927f   // 2*log2(e), folded into W_hh and T2

// column permutation: n = 32w + 16cb2 + c  ->  k' = 32w + 2c + cb2
__device__ __forceinline__ int perm2(int n) {
  return (n & 0xE0) | ((n & 15) << 1) | ((n >> 4) & 1);
}
__device__ __forceinline__ int iperm2(int k) {
  return (k & 0xE0) | ((k & 1) << 4) | ((k >> 1) & 15);
}
// A-storage: granule(row m, octet o) at byte o*256 + ((m ^ (o&3))&15)*16
__device__ __forceinline__ int aaddr2(int m, int o) {
  return o * 256 + (((m ^ (o & 3)) & 15) << 4);
}
// k_out A-tile swizzle
__device__ __forceinline__ int aswz(int b) { return b ^ (((b >> 9) & 7) << 4); }

#define BAR() asm volatile("s_waitcnt lgkmcnt(0)\n\ts_barrier" ::: "memory")

// ---------- prep
__global__ void k_prep(const float* __restrict__ emb, const float* __restrict__ W_ih,
                       const float* __restrict__ b_ih, const float* __restrict__ b_hh,
                       const float* __restrict__ W_ho,
                       _Float16* __restrict__ T2g, _Float16* __restrict__ Wp) {
  int bid = blockIdx.x, tid = threadIdx.x;
  if (bid < Vn) {
    int vv = bid, h = tid;
    const float4* e4 = (const float4*)(emb + vv * En);
    const float4* w4 = (const float4*)(W_ih + h * En);
    float acc = 0.f;
    #pragma unroll
    for (int i = 0; i < En / 4; ++i) {
      float4 a = e4[i], b = w4[i];
      acc += a.x * b.x + a.y * b.y + a.z * b.z + a.w * b.w;
    }
    T2g[vv * Hn + perm2(h)] = (_Float16)((acc + b_ih[h] + b_hh[h]) * LOG2E2);
  } else if (Wp) {
    int vv = bid - Vn, kp = tid;
    Wp[vv * Hn + kp] = (_Float16)W_ho[vv * Hn + iperm2(kp)];
  }
}

#define MFA(ks) \
  accA0 = __builtin_amdgcn_mfma_f32_16x16x32_f16(afA##ks, Bf[0][ks], accA0, 0, 0, 0); \
  accA1 = __builtin_amdgcn_mfma_f32_16x16x32_f16(afA##ks, Bf[1][ks], accA1, 0, 0, 0);
#define MFB(ks) \
  accB0 = __builtin_amdgcn_mfma_f32_16x16x32_f16(afB##ks, Bf[0][ks], accB0, 0, 0, 0); \
  accB1 = __builtin_amdgcn_mfma_f32_16x16x32_f16(afB##ks, Bf[1][ks], accB1, 0, 0, 0);

// ---------- recurrence: 8 blocks x 512 thr (8 waves, 2/SIMD). Each block runs TWO
// independent 16-row recurrences (rows 32b..+16 and +16..+32) interleaved in one
// instruction stream: group B's DS reads / MFMAs fill group A's latency edges and
// vice versa. Shared W_hh B-frags. One lgkm-only barrier per DOUBLE-step.
__global__ __launch_bounds__(512, 1) void k_rnn(const int* __restrict__ inp,
    const float* __restrict__ hidden, const float* __restrict__ W_hh,
    const _Float16* __restrict__ T2g, float* out_base) {
  __shared__ _Float16 AbufA[2 * 16 * Hn];    // 16 KB  fragment-order, dbuf
  __shared__ _Float16 AbufB[2 * 16 * Hn];    // 16 KB
  __shared__ unsigned char idxb[Sn * 32];    // 32 KB  [t][m] m=0..31

  const int tid = threadIdx.x;
  const int l = tid & 63;
  const int w = tid >> 6;   // 0..7
  const int g = l >> 4;     // 0..3
  const int c = l & 15;
  const int bb0 = blockIdx.x << 5;           // 32 rows per block

  // ---- stage idx bytes: 32 rows x 1024 t
  #pragma unroll
  for (int i = 0; i < 16; ++i) {
    int gi = tid + (i << 9);                 // 0..8191
    int m = gi >> 8;                         // 0..31
    int j = gi & 255;                        // int4 index
    int4 d = ((const int4*)(inp + (size_t)(bb0 + m) * Sn))[j];
    int t0 = j << 2;
    idxb[(t0 + 0) * 32 + m] = (unsigned char)d.x;
    idxb[(t0 + 1) * 32 + m] = (unsigned char)d.y;
    idxb[(t0 + 2) * 32 + m] = (unsigned char)d.z;
    idxb[(t0 + 3) * 32 + m] = (unsigned char)d.w;
  }

  // ---- W_hh B-frags (pre-scaled, SHARED by both groups)
  f16x8 Bf[2][8];
  #pragma unroll
  for (int cb2 = 0; cb2 < 2; ++cb2) {
    const float* wrow = W_hh + ((w << 5) + (cb2 << 4) + c) * Hn;
    #pragma unroll
    for (int ks = 0; ks < 8; ++ks) {
      union { _Float16 h[8]; f16x8 v8; } u;
      #pragma unroll
      for (int j = 0; j < 8; ++j)
        u.h[j] = (_Float16)(wrow[iperm2((ks << 5) + (g << 3) + j)] * LOG2E2);
      Bf[cb2][ks] = u.v8;
    }
  }

  // per-thread LDS byte offsets (loop-invariant)
  int ard[8];
  #pragma unroll
  for (int ks = 0; ks < 8; ++ks) ard[ks] = aaddr2(c, (ks << 2) + g);
  int awr[4];
  #pragma unroll
  for (int r = 0; r < 4; ++r)
    awr[r] = aaddr2((g << 2) + r, (w << 2) + (c >> 2)) + ((c & 3) << 2);
  const int xoff = (w << 6) + (c << 2);

  // ---- initial h -> buffers 0
  #pragma unroll
  for (int r = 0; r < 4; ++r) {
    int mA = bb0 + (g << 2) + r;
    int mB = mA + 16;
    union { _Float16 h[2]; u32 q; } ha, hb;
    ha.h[0] = (_Float16)hidden[mA * Hn + (w << 5) + c];
    ha.h[1] = (_Float16)hidden[mA * Hn + (w << 5) + 16 + c];
    hb.h[0] = (_Float16)hidden[mB * Hn + (w << 5) + c];
    hb.h[1] = (_Float16)hidden[mB * Hn + (w << 5) + 16 + c];
    *(u32*)((char*)AbufA + awr[r]) = ha.q;
    *(u32*)((char*)AbufB + awr[r]) = hb.q;
  }

  // ---- x(0) gather from T2g
  const char* T2b = (const char*)T2g;
  f16x2 xvA[4], xvB[4];
  #pragma unroll
  for (int r = 0; r < 4; ++r) {
    u32 vA = (u32)inp[(size_t)(bb0 + (g << 2) + r) * Sn];
    u32 vB = (u32)inp[(size_t)(bb0 + 16 + (g << 2) + r) * Sn];
    xvA[r] = *(const f16x2*)(T2b + (vA << 9) + xoff);
    xvB[r] = *(const f16x2*)(T2b + (vB << 9) + xoff);
  }
  __syncthreads();

  char* outb = (char*)out_base;
  float* hfin = out_base + (size_t)Bn * Sn * Vn;

  u32 voA[4], voB[4];
  #pragma unroll
  for (int r = 0; r < 4; ++r) {
    voA[r] = (u32)(((bb0 + (g << 2) + r) * Sn) * 512) + (u32)xoff;
    voB[r] = (u32)(((bb0 + 16 + (g << 2) + r) * Sn) * 512) + (u32)xoff;
  }

  #pragma unroll 1
  for (int t = 0; t < Sn; ++t) {
    const int roff = (t & 1) << 13;
    const int woff = roff ^ 8192;

    // A-frag reads: group A then group B (16 ds_read_b128, conflict-free)
    const char* abA = (const char*)AbufA + roff;
    const char* abB = (const char*)AbufB + roff;
    f16x8 afA0 = *(const f16x8*)(abA + ard[0]);
    f16x8 afA1 = *(const f16x8*)(abA + ard[1]);
    f16x8 afA2 = *(const f16x8*)(abA + ard[2]);
    f16x8 afA3 = *(const f16x8*)(abA + ard[3]);
    f16x8 afA4 = *(const f16x8*)(abA + ard[4]);
    f16x8 afA5 = *(const f16x8*)(abA + ard[5]);
    f16x8 afA6 = *(const f16x8*)(abA + ard[6]);
    f16x8 afA7 = *(const f16x8*)(abA + ard[7]);
    f16x8 afB0 = *(const f16x8*)(abB + ard[0]);
    f16x8 afB1 = *(const f16x8*)(abB + ard[1]);
    f16x8 afB2 = *(const f16x8*)(abB + ard[2]);
    f16x8 afB3 = *(const f16x8*)(abB + ard[3]);
    f16x8 afB4 = *(const f16x8*)(abB + ard[4]);
    f16x8 afB5 = *(const f16x8*)(abB + ard[5]);
    f16x8 afB6 = *(const f16x8*)(abB + ard[6]);
    f16x8 afB7 = *(const f16x8*)(abB + ard[7]);

    // prefetch x(t+1) for both groups (VMEM, L2-hot)
    int tn = (t + 1 < Sn) ? t + 1 : t;
    u32 ivA = *(const u32*)(idxb + tn * 32 + (g << 2));
    u32 ivB = *(const u32*)(idxb + tn * 32 + 16 + (g << 2));
    f16x2 xnA[4], xnB[4];
    xnA[0] = *(const f16x2*)(T2b + ((ivA & 255u) << 9) + xoff);
    xnA[1] = *(const f16x2*)(T2b + (((ivA >> 8) & 255u) << 9) + xoff);
    xnA[2] = *(const f16x2*)(T2b + (((ivA >> 16) & 255u) << 9) + xoff);
    xnA[3] = *(const f16x2*)(T2b + ((ivA >> 24) << 9) + xoff);
    xnB[0] = *(const f16x2*)(T2b + ((ivB & 255u) << 9) + xoff);
    xnB[1] = *(const f16x2*)(T2b + (((ivB >> 8) & 255u) << 9) + xoff);
    xnB[2] = *(const f16x2*)(T2b + (((ivB >> 16) & 255u) << 9) + xoff);
    xnB[3] = *(const f16x2*)(T2b + ((ivB >> 24) << 9) + xoff);

    // group A: acc init + 16 MFMAs (runs while B's reads drain)
    f32x4 accA0 = { (float)xvA[0][0], (float)xvA[1][0], (float)xvA[2][0], (float)xvA[3][0] };
    f32x4 accA1 = { (float)xvA[0][1], (float)xvA[1][1], (float)xvA[2][1], (float)xvA[3][1] };
    MFA(0) MFA(1) MFA(2) MFA(3) MFA(4) MFA(5) MFA(6) MFA(7)

    // group B: acc init + 16 MFMAs
    f32x4 accB0 = { (float)xvB[0][0], (float)xvB[1][0], (float)xvB[2][0], (float)xvB[3][0] };
    f32x4 accB1 = { (float)xvB[0][1], (float)xvB[1][1], (float)xvB[2][1], (float)xvB[3][1] };
    MFB(0) MFB(1) MFB(2) MFB(3) MFB(4) MFB(5) MFB(6) MFB(7)

    // finalize A (trans/VALU overlaps MFMA pipe draining B)
    char* wbA = (char*)AbufA + woff;
    #pragma unroll
    for (int r = 0; r < 4; ++r) {
      float e0 = __builtin_amdgcn_exp2f(accA0[r]);
      float e1 = __builtin_amdgcn_exp2f(accA1[r]);
      float h0 = fmaf(-2.f, __builtin_amdgcn_rcpf(e0 + 1.f), 1.f);
      float h1 = fmaf(-2.f, __builtin_amdgcn_rcpf(e1 + 1.f), 1.f);
      union { _Float16 h[2]; u32 q; } hp;
      hp.h[0] = (_Float16)h0;
      hp.h[1] = (_Float16)h1;
      *(u32*)(wbA + awr[r]) = hp.q;
      *(u32*)(outb + voA[r]) = hp.q;
      voA[r] += 512;
    }
    // finalize B
    char* wbB = (char*)AbufB + woff;
    #pragma unroll
    for (int r = 0; r < 4; ++r) {
      float e0 = __builtin_amdgcn_exp2f(accB0[r]);
      float e1 = __builtin_amdgcn_exp2f(accB1[r]);
      float h0 = fmaf(-2.f, __builtin_amdgcn_rcpf(e0 + 1.f), 1.f);
      float h1 = fmaf(-2.f, __builtin_amdgcn_rcpf(e1 + 1.f), 1.f);
      union { _Float16 h[2]; u32 q; } hp;
      hp.h[0] = (_Float16)h0;
      hp.h[1] = (_Float16)h1;
      *(u32*)(wbB + awr[r]) = hp.q;
      *(u32*)(outb + voB[r]) = hp.q;
      voB[r] += 512;
    }

    #pragma unroll
    for (int r = 0; r < 4; ++r) { xvA[r] = xnA[r]; xvB[r] = xnB[r]; }

    BAR();   // lgkm drain only; exports stay in flight
  }

  // h_final from final LDS buffers (buffer 0 after t=1023)
  #pragma unroll
  for (int r = 0; r < 4; ++r) {
    int mA = bb0 + (g << 2) + r;
    int mB = mA + 16;
    union { _Float16 h[2]; u32 q; } ha, hb;
    ha.q = *(const u32*)((const char*)AbufA + awr[r]);
    hb.q = *(const u32*)((const char*)AbufB + awr[r]);
    hfin[mA * Hn + (w << 5) + c]      = (float)ha.h[0];
    hfin[mA * Hn + (w << 5) + 16 + c] = (float)ha.h[1];
    hfin[mB * Hn + (w << 5) + c]      = (float)hb.h[0];
    hfin[mB * Hn + (w << 5) + 16 + c] = (float)hb.h[1];
  }
}

// ---------- output GEMM: 4096 blocks x 512 thr (8 waves), in place over d_out.
template <int SLOW>
__global__ __launch_bounds__(512) void k_out(const float* __restrict__ W_ho,
    const float* __restrict__ b_ho, const _Float16* __restrict__ Wp,
    float* out_base) {
  __shared__ _Float16 At[64 * 256];                 // 32 KB, row-swizzled
  __shared__ _Float16 Wl[SLOW ? Vn * Hn : 8];       // 64 KB slow path only
  const int tid = threadIdx.x;
  const int l = tid & 63;
  const int w = tid >> 6;   // 0..7
  const int g = l >> 4;
  const int c = l & 15;
  const size_t m0 = (size_t)blockIdx.x << 6;
  const _Float16* hall = (const _Float16*)out_base;

  {
    const uint4* src = (const uint4*)(hall + (m0 << 8));
    #pragma unroll
    for (int i = 0; i < 4; ++i) {
      int gg = tid + (i << 9);
      int row = gg >> 5;
      int cb16 = (gg & 31) << 4;
      uint4 d = src[gg];
      *(uint4*)((char*)At + ((row * 512 + cb16) ^ ((row & 7) << 4))) = d;
    }
  }

  const int v = (w << 4) + c;
  f16x8 Bf[8];
  if (!SLOW) {
    const _Float16* wrow = Wp + v * Hn;
    #pragma unroll
    for (int ks = 0; ks < 8; ++ks)
      Bf[ks] = *(const f16x8*)(wrow + (ks << 5) + (g << 3));
    __syncthreads();
  } else {
    {
      int sv = tid >> 2;
      int kc = (tid & 3) << 6;
      const float* srcw = W_ho + sv * Hn + kc;
      for (int e = 0; e < 64; ++e) {
        int k = kc + e;
        *(_Float16*)((char*)Wl + ((sv * 512 + (perm2(k) << 1)) ^ ((sv & 7) << 4)))
            = (_Float16)srcw[e];
      }
    }
    __syncthreads();
    #pragma unroll
    for (int ks = 0; ks < 8; ++ks)
      Bf[ks] = *(const f16x8*)((const char*)Wl +
                 ((v * 512 + (ks << 6) + (g << 4)) ^ ((v & 7) << 4)));
  }
  const float bias = b_ho[v];

  #pragma unroll
  for (int mt = 0; mt < 4; ++mt) {
    f32x4 acc = {bias, bias, bias, bias};
    const int row = (mt << 4) + c;
    #pragma unroll
    for (int ks = 0; ks < 8; ++ks) {
      f16x8 a = *(const f16x8*)((const char*)At +
                  ((row * 512 + (ks << 6) + (g << 4)) ^ ((row & 7) << 4)));
      acc = __builtin_amdgcn_mfma_f32_16x16x32_f16(a, Bf[ks], acc, 0, 0, 0);
    }
    float* orow = out_base + (m0 + (mt << 4) + (g << 2)) * Vn + v;
    orow[0]      = acc[0];
    orow[Vn]     = acc[1];
    orow[2 * Vn] = acc[2];
    orow[3 * Vn] = acc[3];
  }
}

extern "C" void kernel_launch(void* const* d_in, const int* in_sizes, int n_in,
                              void* d_out, int out_size, void* d_ws, size_t ws_size,
                              hipStream_t stream) {
  (void)in_sizes; (void)n_in; (void)out_size;
  const int*   inp    = (const int*)  d_in[0];
  const float* hidden = (const float*)d_in[1];
  const float* emb    = (const float*)d_in[2];
  const float* W_ih   = (const float*)d_in[3];
  const float* b_ih   = (const float*)d_in[4];
  const float* W_hh   = (const float*)d_in[5];
  const float* b_hh   = (const float*)d_in[6];
  const float* W_ho   = (const float*)d_in[7];
  const float* b_ho   = (const float*)d_in[8];
  float* out = (float*)d_out;

  const bool useWs = (ws_size >= 131072);
  _Float16* T2g = useWs ? (_Float16*)d_ws
                        : (_Float16*)(out + (size_t)Bn * Sn * Vn);
  _Float16* Wp  = useWs ? (_Float16*)((char*)d_ws + 65536) : nullptr;

  k_prep<<<dim3(useWs ? 2 * Vn : Vn), dim3(Hn), 0, stream>>>(emb, W_ih, b_ih, b_hh,
                                                             W_ho, T2g, Wp);
  k_rnn<<<dim3(Bn / 32), dim3(512), 0, stream>>>(inp, hidden, W_hh, T2g, out);
  if (useWs)
    k_out<0><<<dim3((Bn * Sn) / 64), dim3(512), 0, stream>>>(W_ho, b_ho, Wp, out);
  else
    k_out<1><<<dim3((Bn * Sn) / 64), dim3(512), 0, stream>>>(W_ho, b_ho, nullptr, out);
}

// Round 13
// 667.255 us; speedup vs baseline: 1.9828x; 1.9828x over previous
//
#include <hip/hip_runtime.h>
#include <hip/hip_bf16.h>
#include <hip/hip_fp16.h>

#define Bn 256
#define Sn 1024
#define Hn 256
#define Vn 128
#define En 128

typedef _Float16 f16x8 __attribute__((ext_vector_type(8)));
typedef _Float16 f16x2 __attribute__((ext_vector_type(2)));
typedef float f32x4 __attribute__((ext_vector_type(4)));
typedef unsigned long long u64;
typedef unsigned int u32;

#define LOG2E2 2.885390081777927f   // 2*log2(e), folded into W_hh and T2

// column permutation: n = 32w + 16cb2 + c  ->  k' = 32w + 2c + cb2
__device__ __forceinline__ int perm2(int n) {
  return (n & 0xE0) | ((n & 15) << 1) | ((n >> 4) & 1);
}
__device__ __forceinline__ int iperm2(int k) {
  return (k & 0xE0) | ((k & 1) << 4) | ((k >> 1) & 15);
}
// A-storage: granule(row m, octet o) at byte o*256 + ((m ^ (o&3))&15)*16
__device__ __forceinline__ int aaddr2(int m, int o) {
  return o * 256 + (((m ^ (o & 3)) & 15) << 4);
}
// k_out A-tile swizzle
__device__ __forceinline__ int aswz(int b) { return b ^ (((b >> 9) & 7) << 4); }

#define BAR() asm volatile("s_waitcnt lgkmcnt(0)\n\ts_barrier" ::: "memory")

// ---------- prep
__global__ void k_prep(const float* __restrict__ emb, const float* __restrict__ W_ih,
                       const float* __restrict__ b_ih, const float* __restrict__ b_hh,
                       const float* __restrict__ W_ho,
                       _Float16* __restrict__ T2g, _Float16* __restrict__ Wp) {
  int bid = blockIdx.x, tid = threadIdx.x;
  if (bid < Vn) {
    int vv = bid, h = tid;
    const float4* e4 = (const float4*)(emb + vv * En);
    const float4* w4 = (const float4*)(W_ih + h * En);
    float acc = 0.f;
    #pragma unroll
    for (int i = 0; i < En / 4; ++i) {
      float4 a = e4[i], b = w4[i];
      acc += a.x * b.x + a.y * b.y + a.z * b.z + a.w * b.w;
    }
    T2g[vv * Hn + perm2(h)] = (_Float16)((acc + b_ih[h] + b_hh[h]) * LOG2E2);
  } else if (Wp) {
    int vv = bid - Vn, kp = tid;
    Wp[vv * Hn + kp] = (_Float16)W_ho[vv * Hn + iperm2(kp)];
  }
}

// ---------- recurrence: 16 blocks x 512 thr (8 waves, 2/SIMD). Wave w: cols [32w,32w+32),
// full K=256, conflict-free fragment-order A layout. t-loop unrolled x2 so LDS buffer
// offsets are compile-time (fold into ds offset immediates). setprio around MFMAs.
__global__ __launch_bounds__(512, 1) void k_rnn(const int* __restrict__ inp,
    const float* __restrict__ hidden, const float* __restrict__ W_hh,
    const _Float16* __restrict__ T2g, float* out_base) {
  __shared__ _Float16 Abuf[2 * 16 * Hn];     // 16 KB  fragment-order, dbuf
  __shared__ unsigned char idxb[Sn * 16];    // 16 KB  [t][m]

  const int tid = threadIdx.x;
  const int l = tid & 63;
  const int w = tid >> 6;   // 0..7
  const int g = l >> 4;     // 0..3
  const int c = l & 15;
  const int bb0 = blockIdx.x << 4;

  // ---- stage idx bytes
  #pragma unroll
  for (int i = 0; i < 8; ++i) {
    int gi = tid + (i << 9);
    int m = gi >> 8;
    int j = gi & 255;
    int4 d = ((const int4*)(inp + (size_t)(bb0 + m) * Sn))[j];
    int t0 = j << 2;
    idxb[(t0 + 0) * 16 + m] = (unsigned char)d.x;
    idxb[(t0 + 1) * 16 + m] = (unsigned char)d.y;
    idxb[(t0 + 2) * 16 + m] = (unsigned char)d.z;
    idxb[(t0 + 3) * 16 + m] = (unsigned char)d.w;
  }

  // ---- W_hh B-frags (pre-scaled)
  f16x8 Bf[2][8];
  #pragma unroll
  for (int cb2 = 0; cb2 < 2; ++cb2) {
    const float* wrow = W_hh + ((w << 5) + (cb2 << 4) + c) * Hn;
    #pragma unroll
    for (int ks = 0; ks < 8; ++ks) {
      union { _Float16 h[8]; f16x8 v8; } u;
      #pragma unroll
      for (int j = 0; j < 8; ++j)
        u.h[j] = (_Float16)(wrow[iperm2((ks << 5) + (g << 3) + j)] * LOG2E2);
      Bf[cb2][ks] = u.v8;
    }
  }

  // per-thread LDS byte offsets (loop-invariant)
  int ard[8];
  #pragma unroll
  for (int ks = 0; ks < 8; ++ks) ard[ks] = aaddr2(c, (ks << 2) + g);
  int awr[4];
  #pragma unroll
  for (int r = 0; r < 4; ++r)
    awr[r] = aaddr2((g << 2) + r, (w << 2) + (c >> 2)) + ((c & 3) << 2);
  const int xoff = (w << 6) + (c << 2);

  // ---- initial h -> buffer 0
  #pragma unroll
  for (int r = 0; r < 4; ++r) {
    int m = (g << 2) + r;
    union { _Float16 h[2]; u32 q; } hp;
    hp.h[0] = (_Float16)hidden[(bb0 + m) * Hn + (w << 5) + c];
    hp.h[1] = (_Float16)hidden[(bb0 + m) * Hn + (w << 5) + 16 + c];
    *(u32*)((char*)Abuf + awr[r]) = hp.q;
  }

  // ---- x(0)
  const char* T2b = (const char*)T2g;
  f16x2 xv[4];
  #pragma unroll
  for (int r = 0; r < 4; ++r) {
    u32 v0 = (u32)inp[(size_t)(bb0 + (g << 2) + r) * Sn];
    xv[r] = *(const f16x2*)(T2b + (v0 << 9) + xoff);
  }
  __syncthreads();

  char* outb = (char*)out_base;
  float* hfin = out_base + (size_t)Bn * Sn * Vn;

  u32 vo[4];
  #pragma unroll
  for (int r = 0; r < 4; ++r)
    vo[r] = (u32)(((bb0 + (g << 2) + r) * Sn) * 512) + (u32)xoff;

  // One full step: reads at compile-time RO, writes at compile-time WO.
  // TN = t-index whose x we prefetch (uniform).
#define RNN_STEP(RO, WO, TN)                                                        \
  {                                                                                 \
    const char* ab = (const char*)Abuf + (RO);                                      \
    f16x8 af0 = *(const f16x8*)(ab + ard[0]);                                       \
    f16x8 af1 = *(const f16x8*)(ab + ard[1]);                                       \
    f16x8 af2 = *(const f16x8*)(ab + ard[2]);                                       \
    f16x8 af3 = *(const f16x8*)(ab + ard[3]);                                       \
    f16x8 af4 = *(const f16x8*)(ab + ard[4]);                                       \
    f16x8 af5 = *(const f16x8*)(ab + ard[5]);                                       \
    f16x8 af6 = *(const f16x8*)(ab + ard[6]);                                       \
    f16x8 af7 = *(const f16x8*)(ab + ard[7]);                                       \
    u32 iv = *(const u32*)(idxb + (TN) * 16 + (g << 2));                            \
    f16x2 xn[4];                                                                    \
    xn[0] = *(const f16x2*)(T2b + ((iv & 255u) << 9) + xoff);                       \
    xn[1] = *(const f16x2*)(T2b + (((iv >> 8) & 255u) << 9) + xoff);                \
    xn[2] = *(const f16x2*)(T2b + (((iv >> 16) & 255u) << 9) + xoff);               \
    xn[3] = *(const f16x2*)(T2b + ((iv >> 24) << 9) + xoff);                        \
    f32x4 acc0 = { (float)xv[0][0], (float)xv[1][0], (float)xv[2][0], (float)xv[3][0] }; \
    f32x4 acc1 = { (float)xv[0][1], (float)xv[1][1], (float)xv[2][1], (float)xv[3][1] }; \
    __builtin_amdgcn_s_setprio(1);                                                  \
    acc0 = __builtin_amdgcn_mfma_f32_16x16x32_f16(af0, Bf[0][0], acc0, 0, 0, 0);    \
    acc1 = __builtin_amdgcn_mfma_f32_16x16x32_f16(af0, Bf[1][0], acc1, 0, 0, 0);    \
    acc0 = __builtin_amdgcn_mfma_f32_16x16x32_f16(af1, Bf[0][1], acc0, 0, 0, 0);    \
    acc1 = __builtin_amdgcn_mfma_f32_16x16x32_f16(af1, Bf[1][1], acc1, 0, 0, 0);    \
    acc0 = __builtin_amdgcn_mfma_f32_16x16x32_f16(af2, Bf[0][2], acc0, 0, 0, 0);    \
    acc1 = __builtin_amdgcn_mfma_f32_16x16x32_f16(af2, Bf[1][2], acc1, 0, 0, 0);    \
    acc0 = __builtin_amdgcn_mfma_f32_16x16x32_f16(af3, Bf[0][3], acc0, 0, 0, 0);    \
    acc1 = __builtin_amdgcn_mfma_f32_16x16x32_f16(af3, Bf[1][3], acc1, 0, 0, 0);    \
    acc0 = __builtin_amdgcn_mfma_f32_16x16x32_f16(af4, Bf[0][4], acc0, 0, 0, 0);    \
    acc1 = __builtin_amdgcn_mfma_f32_16x16x32_f16(af4, Bf[1][4], acc1, 0, 0, 0);    \
    acc0 = __builtin_amdgcn_mfma_f32_16x16x32_f16(af5, Bf[0][5], acc0, 0, 0, 0);    \
    acc1 = __builtin_amdgcn_mfma_f32_16x16x32_f16(af5, Bf[1][5], acc1, 0, 0, 0);    \
    acc0 = __builtin_amdgcn_mfma_f32_16x16x32_f16(af6, Bf[0][6], acc0, 0, 0, 0);    \
    acc1 = __builtin_amdgcn_mfma_f32_16x16x32_f16(af6, Bf[1][6], acc1, 0, 0, 0);    \
    acc0 = __builtin_amdgcn_mfma_f32_16x16x32_f16(af7, Bf[0][7], acc0, 0, 0, 0);    \
    acc1 = __builtin_amdgcn_mfma_f32_16x16x32_f16(af7, Bf[1][7], acc1, 0, 0, 0);    \
    __builtin_amdgcn_s_setprio(0);                                                  \
    char* wb = (char*)Abuf + (WO);                                                  \
    _Pragma("unroll")                                                               \
    for (int r = 0; r < 4; ++r) {                                                   \
      float e0 = __builtin_amdgcn_exp2f(acc0[r]);                                   \
      float e1 = __builtin_amdgcn_exp2f(acc1[r]);                                   \
      float h0 = fmaf(-2.f, __builtin_amdgcn_rcpf(e0 + 1.f), 1.f);                  \
      float h1 = fmaf(-2.f, __builtin_amdgcn_rcpf(e1 + 1.f), 1.f);                  \
      union { _Float16 h[2]; u32 q; } hp;                                           \
      hp.h[0] = (_Float16)h0;                                                       \
      hp.h[1] = (_Float16)h1;                                                       \
      *(u32*)(wb + awr[r]) = hp.q;                                                  \
      *(u32*)(outb + vo[r]) = hp.q;                                                 \
      vo[r] += 512;                                                                 \
    }                                                                               \
    _Pragma("unroll")                                                               \
    for (int r = 0; r < 4; ++r) xv[r] = xn[r];                                      \
    BAR();                                                                          \
  }

  #pragma unroll 1
  for (int t2 = 0; t2 < Sn; t2 += 2) {
    // step t2:   read buf0, write buf1; prefetch x(t2+1) (always valid)
    RNN_STEP(0, 8192, (t2 + 1))
    // step t2+1: read buf1, write buf0; prefetch x(t2+2) clamped (uniform scalar)
    int tn2 = (t2 + 2 < Sn) ? (t2 + 2) : (Sn - 1);
    RNN_STEP(8192, 0, tn2)
  }
#undef RNN_STEP

  // h_final from buffer 0 (after even number of steps)
  #pragma unroll
  for (int r = 0; r < 4; ++r) {
    int m = (g << 2) + r;
    union { _Float16 h[2]; u32 q; } hp;
    hp.q = *(const u32*)((const char*)Abuf + awr[r]);
    hfin[(bb0 + m) * Hn + (w << 5) + c]      = (float)hp.h[0];
    hfin[(bb0 + m) * Hn + (w << 5) + 16 + c] = (float)hp.h[1];
  }
}

// ---------- output GEMM: 4096 blocks x 512 thr (8 waves), in place over d_out.
template <int SLOW>
__global__ __launch_bounds__(512) void k_out(const float* __restrict__ W_ho,
    const float* __restrict__ b_ho, const _Float16* __restrict__ Wp,
    float* out_base) {
  __shared__ _Float16 At[64 * 256];                 // 32 KB, row-swizzled
  __shared__ _Float16 Wl[SLOW ? Vn * Hn : 8];       // 64 KB slow path only
  const int tid = threadIdx.x;
  const int l = tid & 63;
  const int w = tid >> 6;   // 0..7
  const int g = l >> 4;
  const int c = l & 15;
  const size_t m0 = (size_t)blockIdx.x << 6;
  const _Float16* hall = (const _Float16*)out_base;

  {
    const uint4* src = (const uint4*)(hall + (m0 << 8));
    #pragma unroll
    for (int i = 0; i < 4; ++i) {
      int gg = tid + (i << 9);
      int row = gg >> 5;
      int cb16 = (gg & 31) << 4;
      uint4 d = src[gg];
      *(uint4*)((char*)At + ((row * 512 + cb16) ^ ((row & 7) << 4))) = d;
    }
  }

  const int v = (w << 4) + c;
  f16x8 Bf[8];
  if (!SLOW) {
    const _Float16* wrow = Wp + v * Hn;
    #pragma unroll
    for (int ks = 0; ks < 8; ++ks)
      Bf[ks] = *(const f16x8*)(wrow + (ks << 5) + (g << 3));
    __syncthreads();
  } else {
    {
      int sv = tid >> 2;
      int kc = (tid & 3) << 6;
      const float* srcw = W_ho + sv * Hn + kc;
      for (int e = 0; e < 64; ++e) {
        int k = kc + e;
        *(_Float16*)((char*)Wl + ((sv * 512 + (perm2(k) << 1)) ^ ((sv & 7) << 4)))
            = (_Float16)srcw[e];
      }
    }
    __syncthreads();
    #pragma unroll
    for (int ks = 0; ks < 8; ++ks)
      Bf[ks] = *(const f16x8*)((const char*)Wl +
                 ((v * 512 + (ks << 6) + (g << 4)) ^ ((v & 7) << 4)));
  }
  const float bias = b_ho[v];

  #pragma unroll
  for (int mt = 0; mt < 4; ++mt) {
    f32x4 acc = {bias, bias, bias, bias};
    const int row = (mt << 4) + c;
    #pragma unroll
    for (int ks = 0; ks < 8; ++ks) {
      f16x8 a = *(const f16x8*)((const char*)At +
                  ((row * 512 + (ks << 6) + (g << 4)) ^ ((row & 7) << 4)));
      acc = __builtin_amdgcn_mfma_f32_16x16x32_f16(a, Bf[ks], acc, 0, 0, 0);
    }
    float* orow = out_base + (m0 + (mt << 4) + (g << 2)) * Vn + v;
    orow[0]      = acc[0];
    orow[Vn]     = acc[1];
    orow[2 * Vn] = acc[2];
    orow[3 * Vn] = acc[3];
  }
}

extern "C" void kernel_launch(void* const* d_in, const int* in_sizes, int n_in,
                              void* d_out, int out_size, void* d_ws, size_t ws_size,
                              hipStream_t stream) {
  (void)in_sizes; (void)n_in; (void)out_size;
  const int*   inp    = (const int*)  d_in[0];
  const float* hidden = (const float*)d_in[1];
  const float* emb    = (const float*)d_in[2];
  const float* W_ih   = (const float*)d_in[3];
  const float* b_ih   = (const float*)d_in[4];
  const float* W_hh   = (const float*)d_in[5];
  const float* b_hh   = (const float*)d_in[6];
  const float* W_ho   = (const float*)d_in[7];
  const float* b_ho   = (const float*)d_in[8];
  float* out = (float*)d_out;

  const bool useWs = (ws_size >= 131072);
  _Float16* T2g = useWs ? (_Float16*)d_ws
                        : (_Float16*)(out + (size_t)Bn * Sn * Vn);
  _Float16* Wp  = useWs ? (_Float16*)((char*)d_ws + 65536) : nullptr;

  k_prep<<<dim3(useWs ? 2 * Vn : Vn), dim3(Hn), 0, stream>>>(emb, W_ih, b_ih, b_hh,
                                                             W_ho, T2g, Wp);
  k_rnn<<<dim3(Bn / 16), dim3(512), 0, stream>>>(inp, hidden, W_hh, T2g, out);
  if (useWs)
    k_out<0><<<dim3((Bn * Sn) / 64), dim3(512), 0, stream>>>(W_ho, b_ho, Wp, out);
  else
    k_out<1><<<dim3((Bn * Sn) / 64), dim3(512), 0, stream>>>(W_ho, b_ho, nullptr, out);
}